// Round 12
// baseline (354.631 us; speedup 1.0000x reference)
//
#include <hip/hip_runtime.h>
#include <hip/hip_bf16.h>
#include <stdint.h>

#define H_  16
#define S_  2048
#define D_  2048
#define HD_ 128

typedef __bf16 bf16x8 __attribute__((ext_vector_type(8)));
typedef short  s16x8  __attribute__((ext_vector_type(8)));
typedef float  f32x4  __attribute__((ext_vector_type(4)));
typedef unsigned short u16x4 __attribute__((ext_vector_type(4)));

__device__ __forceinline__ unsigned short f2bf(float f) {
    unsigned u = __builtin_bit_cast(unsigned, f);
    u += 0x7fffu + ((u >> 16) & 1u);
    return (unsigned short)(u >> 16);
}

__device__ __forceinline__ bf16x8 ld_bf8(const unsigned short* p) {
    s16x8 r = *reinterpret_cast<const s16x8*>(p);
    return __builtin_bit_cast(bf16x8, r);
}

#define GLOAD_LDS16(gp, lp)                                                     \
    __builtin_amdgcn_global_load_lds(                                            \
        (const __attribute__((address_space(1))) void*)(gp),                     \
        (__attribute__((address_space(3))) void*)(lp), 16, 0, 0)

// ---------------- cast fp32 -> bf16 ----------------
__global__ __launch_bounds__(256) void cast_f32_bf16(const float* __restrict__ in,
                                                     unsigned short* __restrict__ out,
                                                     int n) {
    int i = (blockIdx.x * 256 + threadIdx.x) * 4;
    if (i >= n) return;
    float4 v = *reinterpret_cast<const float4*>(in + i);
    u16x4 o;
    o[0] = f2bf(v.x); o[1] = f2bf(v.y); o[2] = f2bf(v.z); o[3] = f2bf(v.w);
    *reinterpret_cast<u16x4*>(out + i) = o;
}

// ======= counted-vmcnt triple-buffered GEMM core (T3/T4, race-free 3-buffer) =======
// BM=256 (A rows), BN=128 (B rows), BK=64. 8 waves (512 thr): wm=w>>1 (4), wn=w&1 (2).
// Wave output 64x64 = acc[4][4]. Per iter: stage tile t+2 (6 gload_lds/thread),
// compute tile t, s_waitcnt vmcnt(6) + raw s_barrier (tile t+1 landed; never vmcnt(0)
// in steady state). Buffer t-1 is fully consumed when t+2 stages into its slot.
__device__ __forceinline__ void gemm3_core(const unsigned short* __restrict__ Aptr,
                                           const unsigned short* __restrict__ Bptr,
                                           int m0, int n0, f32x4 acc[4][4]) {
    __shared__ alignas(16) unsigned short As3[3][256 * 64];
    __shared__ alignas(16) unsigned short Bs3[3][128 * 64];
    const int t  = threadIdx.x;
    const int l  = t & 63, w = t >> 6;
    const int wm = w >> 1, wn = w & 1;
    const int lr = l & 15, g = l >> 4;

    f32x4 zero = {0.f, 0.f, 0.f, 0.f};
#pragma unroll
    for (int i = 0; i < 4; ++i)
#pragma unroll
        for (int j = 0; j < 4; ++j) acc[i][j] = zero;

    auto STAGE = [&](int buf, int kt) {
#pragma unroll
        for (int p = 0; p < 4; ++p) {
            int lin = (p * 512 + t) * 16;          // byte offset in A tile [256][128B]
            int row = lin >> 7, colb = lin & 127;
            int scol = (colb ^ ((row & 7) << 4)) >> 1;
            GLOAD_LDS16(Aptr + (size_t)(m0 + row) * D_ + kt + scol, &As3[buf][lin >> 1]);
        }
#pragma unroll
        for (int p = 0; p < 2; ++p) {
            int lin = (p * 512 + t) * 16;          // byte offset in B tile [128][128B]
            int row = lin >> 7, colb = lin & 127;
            int scol = (colb ^ ((row & 7) << 4)) >> 1;
            GLOAD_LDS16(Bptr + (size_t)(n0 + row) * D_ + kt + scol, &Bs3[buf][lin >> 1]);
        }
    };

    STAGE(0, 0);
    STAGE(1, 64);
    asm volatile("s_waitcnt vmcnt(6)" ::: "memory");   // tile0's 6 loads done
    __builtin_amdgcn_s_barrier();

    const int NT = D_ / 64;
    int bsel = 0;
    for (int tt = 0; tt < NT; ++tt) {
        int s2 = bsel + 2; if (s2 >= 3) s2 -= 3;
        if (tt + 2 < NT) STAGE(s2, (tt + 2) * 64);

        const unsigned short* Ab = As3[bsel];
        const unsigned short* Bb = Bs3[bsel];
        bf16x8 af[4][2], bfr[4][2];
#pragma unroll
        for (int mi = 0; mi < 4; ++mi)
#pragma unroll
            for (int ks = 0; ks < 2; ++ks)
                af[mi][ks] = ld_bf8(&Ab[(wm * 64 + mi * 16 + lr) * 64 +
                                        ((ks * 32 + g * 8) ^ ((lr & 7) << 3))]);
#pragma unroll
        for (int ni = 0; ni < 4; ++ni)
#pragma unroll
            for (int ks = 0; ks < 2; ++ks)
                bfr[ni][ks] = ld_bf8(&Bb[(wn * 64 + ni * 16 + lr) * 64 +
                                         ((ks * 32 + g * 8) ^ ((lr & 7) << 3))]);
#pragma unroll
        for (int ks = 0; ks < 2; ++ks)
#pragma unroll
            for (int mi = 0; mi < 4; ++mi)
#pragma unroll
                for (int ni = 0; ni < 4; ++ni)
                    acc[mi][ni] = __builtin_amdgcn_mfma_f32_16x16x32_bf16(
                        af[mi][ks], bfr[ni][ks], acc[mi][ni], 0, 0, 0);

        if (tt + 1 < NT) {
            if (tt + 2 < NT) { asm volatile("s_waitcnt vmcnt(6)" ::: "memory"); }
            else             { asm volatile("s_waitcnt vmcnt(0)" ::: "memory"); }
            __builtin_amdgcn_s_barrier();              // next tile resident for all waves
        }
        ++bsel; if (bsel == 3) bsel = 0;
    }
}

// ---------------- QKV GEMM (triple-buffered): scatter Q/K [B,H,S,hd], V as [B,H,hd,S] ----
__global__ __launch_bounds__(512) void gemm3_qkv(const unsigned short* __restrict__ Aptr,
                                                 const unsigned short* __restrict__ Bptr,
                                                 const float* __restrict__ bias,
                                                 unsigned short* __restrict__ Qo,
                                                 unsigned short* __restrict__ Ko,
                                                 unsigned short* __restrict__ Vo) {
    // grid 768 = 16 m-tiles x 48 n-tiles; bijective XCD swizzle
    const int raw = blockIdx.x;
    const int swz = (raw & 7) * 96 + (raw >> 3);
    const int m0 = (swz / 48) * 256, n0 = (swz % 48) * 128;

    f32x4 acc[4][4];
    gemm3_core(Aptr, Bptr, m0, n0, acc);

    const int l  = threadIdx.x & 63, w = threadIdx.x >> 6;
    const int wm = w >> 1, wn = w & 1;
    const int lr = l & 15, g = l >> 4;

    for (int mi = 0; mi < 4; ++mi) {
        for (int ni = 0; ni < 4; ++ni) {
            for (int i = 0; i < 4; ++i) {
                int m = m0 + wm * 64 + mi * 16 + g * 4 + i;
                int n = n0 + wn * 64 + ni * 16 + lr;
                float v = acc[mi][ni][i] + bias[n];
                int which = n >> 11;
                int n2 = n & 2047;
                int h = n2 >> 7;
                int d = n2 & 127;
                int b = m >> 11;
                int s = m & 2047;
                unsigned short bv = f2bf(v);
                if (which == 0)
                    Qo[(((size_t)(b * H_ + h)) * S_ + s) * HD_ + d] = bv;
                else if (which == 1)
                    Ko[(((size_t)(b * H_ + h)) * S_ + s) * HD_ + d] = bv;
                else  // V transposed in-epilogue: [B,H,hd,S]
                    Vo[(((size_t)(b * H_ + h)) * HD_ + d) * S_ + s] = bv;
            }
        }
    }
}

// ---------------- output GEMM (triple-buffered): out = O @ Wout^T + b (fp32) ----------
__global__ __launch_bounds__(512) void gemm3_out(const unsigned short* __restrict__ Aptr,
                                                 const unsigned short* __restrict__ Bptr,
                                                 const float* __restrict__ bias,
                                                 float* __restrict__ out) {
    // grid 256 = 16 m-tiles x 16 n-tiles; bijective XCD swizzle
    const int raw = blockIdx.x;
    const int swz = (raw & 7) * 32 + (raw >> 3);
    const int m0 = (swz / 16) * 256, n0 = (swz % 16) * 128;

    f32x4 acc[4][4];
    gemm3_core(Aptr, Bptr, m0, n0, acc);

    const int l  = threadIdx.x & 63, w = threadIdx.x >> 6;
    const int wm = w >> 1, wn = w & 1;
    const int lr = l & 15, g = l >> 4;

    for (int mi = 0; mi < 4; ++mi) {
        for (int ni = 0; ni < 4; ++ni) {
            for (int i = 0; i < 4; ++i) {
                int m = m0 + wm * 64 + mi * 16 + g * 4 + i;
                int n = n0 + wn * 64 + ni * 16 + lr;
                out[(size_t)m * D_ + n] = acc[mi][ni][i] + bias[n];
            }
        }
    }
}

// ---------------- fused attention v10: 32-key chunks, 36 KB LDS -> 4 blocks/CU ----------
__global__ __launch_bounds__(256) void attn_kernel10(const unsigned short* __restrict__ Q,
                                                     const unsigned short* __restrict__ K,
                                                     const unsigned short* __restrict__ Vt,
                                                     const float* __restrict__ biasPtr,
                                                     unsigned short* __restrict__ O) {
    __shared__ alignas(16) unsigned short Klds[2][4096];      // [32][128] bf16 x2 = 16 KB
    __shared__ alignas(16) unsigned short Vlds[2][4096];      // [128][32] bf16 x2 = 16 KB
    __shared__ alignas(16) unsigned short Pbuf[4][16 * 32];   // 4 KB, per-wave

    const int t  = threadIdx.x;
    const int l  = t & 63, w = t >> 6;
    const int lr = l & 15, g = l >> 4;

    const int raw   = blockIdx.x;          // 0..1023
    const int xcd   = raw & 7;
    const int local = raw >> 3;            // 0..127
    const int cu    = local & 31;
    const int slot  = local >> 5;          // 0..3
    const int qt    = (slot & 1) ? cu : (31 - cu);
    const int bh    = xcd + 8 * slot;      // 0..31
    const int b     = bh >> 4, head = bh & 15;

    const unsigned short* Qb = Q + (size_t)bh * S_ * HD_;
    const unsigned short* Kb = K + (size_t)bh * S_ * HD_;
    const unsigned short* Vb = Vt + (size_t)bh * HD_ * S_;
    const float* Bh32 = biasPtr + (size_t)head * S_ * S_;
    const float scale = 0.08838834764831845f;  // 1/sqrt(128)

    const int q0 = qt * 64 + w * 16;

    bf16x8 qf[4];
#pragma unroll
    for (int dc = 0; dc < 4; ++dc)
        qf[dc] = ld_bf8(Qb + (size_t)(q0 + lr) * HD_ + dc * 32 + g * 8);

    f32x4 zero = {0.f, 0.f, 0.f, 0.f};
    f32x4 o[8];
#pragma unroll
    for (int nc = 0; nc < 8; ++nc) o[nc] = zero;
    float lp[4] = {0.f, 0.f, 0.f, 0.f};

    unsigned short* Pw = Pbuf[w];

    auto STAGE = [&](int buf, int k0) {
#pragma unroll
        for (int p = 0; p < 2; ++p) {
            int lin = p * 4096 + t * 16;           // byte offset in K tile
            int row = lin >> 8;                    // 0..31
            int colb = lin & 255;
            int scolb = colb ^ ((row & 7) << 4);
            GLOAD_LDS16(Kb + (size_t)(k0 + row) * HD_ + (scolb >> 1), &Klds[buf][lin >> 1]);
        }
#pragma unroll
        for (int p = 0; p < 2; ++p) {
            int lin = p * 4096 + t * 16;           // byte offset in Vt tile
            int row = lin >> 6;                    // 0..127 (head dim)
            int colb = lin & 63;
            int scolb = colb ^ ((row & 3) << 4);
            GLOAD_LDS16(Vb + (size_t)row * S_ + k0 + (scolb >> 1), &Vlds[buf][lin >> 1]);
        }
    };

    STAGE(0, 0);
    __syncthreads();

    const int nch = 2 * qt + 2;            // 32-key chunks
    int cur = 0;
    for (int c = 0; c < nch; ++c) {
        const int k0 = c * 32;

        if (c + 1 < nch) STAGE(cur ^ 1, k0 + 32);

        // ---- bias -> registers (fp32 direct; independent loads overlap compute)
        float bias_r[4][2];
#pragma unroll
        for (int i = 0; i < 4; ++i) {
            const int boff = (q0 + g * 4 + i) * S_ + k0 + lr;
#pragma unroll
            for (int kc = 0; kc < 2; ++kc)
                bias_r[i][kc] = Bh32[boff + kc * 16];
        }

        // ---- QK^T from swizzled K LDS (16 q-rows x 32 keys)
        f32x4 s[2];
        s[0] = zero; s[1] = zero;
#pragma unroll
        for (int kc = 0; kc < 2; ++kc) {
            bf16x8 kf[4];
#pragma unroll
            for (int dc = 0; dc < 4; ++dc)
                kf[dc] = ld_bf8(&Klds[cur][(kc * 16 + lr) * 128 + ((dc * 32 + g * 8) ^ ((lr & 7) << 3))]);
#pragma unroll
            for (int dc = 0; dc < 4; ++dc)
                s[kc] = __builtin_amdgcn_mfma_f32_16x16x32_bf16(qf[dc], kf[dc], s[kc], 0, 0, 0);
        }

        // ---- softmax (fixed shift), P -> per-wave LDS [16][32]
        const bool maskzone = (c >= nch - 2);
#pragma unroll
        for (int i = 0; i < 4; ++i) {
            const int rowabs = q0 + g * 4 + i;
            const int prow   = g * 4 + i;
            float e[2];
#pragma unroll
            for (int kc = 0; kc < 2; ++kc) {
                float v = s[kc][i] * scale + bias_r[i][kc];
                if (maskzone && (k0 + kc * 16 + lr > rowabs)) v = -1.0e30f;
                e[kc] = __expf(v - 16.0f);
            }
            lp[i] += e[0] + e[1];
            const int sw = (prow & 3) << 3;
            Pw[(prow * 32 + 0  + lr) ^ sw] = f2bf(e[0]);
            Pw[(prow * 32 + 16 + lr) ^ sw] = f2bf(e[1]);
        }

        // ---- PV from swizzled V LDS (K=32: single A-fragment per output tile)
        {
            bf16x8 pa = ld_bf8(&Pw[lr * 32 + ((g * 8) ^ ((lr & 3) << 3))]);
#pragma unroll
            for (int nc = 0; nc < 8; ++nc) {
                bf16x8 vf = ld_bf8(&Vlds[cur][(nc * 16 + lr) * 32 + ((g * 8) ^ ((lr & 3) << 3))]);
                o[nc] = __builtin_amdgcn_mfma_f32_16x16x32_bf16(pa, vf, o[nc], 0, 0, 0);
            }
        }

        __syncthreads();   // drains vmcnt: next-chunk staging complete
        cur ^= 1;
    }

    // one-time cross-lane reduction of row sums (over the 16 lr lanes)
#pragma unroll
    for (int i = 0; i < 4; ++i) {
        lp[i] += __shfl_xor(lp[i], 1);
        lp[i] += __shfl_xor(lp[i], 2);
        lp[i] += __shfl_xor(lp[i], 4);
        lp[i] += __shfl_xor(lp[i], 8);
    }

#pragma unroll
    for (int i = 0; i < 4; ++i) {
        float inv = 1.0f / lp[i];
        int row = q0 + g * 4 + i;
#pragma unroll
        for (int nc = 0; nc < 8; ++nc) {
            O[((size_t)(b * S_ + row)) * D_ + head * HD_ + nc * 16 + lr] = f2bf(o[nc][i] * inv);
        }
    }
}

extern "C" void kernel_launch(void* const* d_in, const int* in_sizes, int n_in,
                              void* d_out, int out_size, void* d_ws, size_t ws_size,
                              hipStream_t stream) {
    (void)in_sizes; (void)n_in; (void)out_size; (void)ws_size;
    const float* x         = (const float*)d_in[0];
    const float* attn_bias = (const float*)d_in[1];
    const float* Wqkv_w    = (const float*)d_in[2];
    const float* Wqkv_b    = (const float*)d_in[3];
    const float* out_w     = (const float*)d_in[4];
    const float* out_b     = (const float*)d_in[5];
    float* out = (float*)d_out;

    char* ws = (char*)d_ws;
    unsigned short* xb    = (unsigned short*)(ws);                 // 16 MB [B*S, D] bf16
    unsigned short* wqkvb = (unsigned short*)(ws + 16777216);      // 24 MB [3D, D] bf16
    unsigned short* woutb = (unsigned short*)(ws + 41943040);      // 8 MB  [D, D] bf16
    unsigned short* Qb    = (unsigned short*)(ws + 50331648);      // 16 MB [B,H,S,hd]
    unsigned short* Kb    = (unsigned short*)(ws + 67108864);      // 16 MB [B,H,S,hd]
    unsigned short* Vtb   = (unsigned short*)(ws + 83886080);      // 16 MB [B,H,hd,S] (direct)
    unsigned short* Ob    = xb;      // reuse (x consumed by QKV GEMM)

    cast_f32_bf16<<<8192, 256, 0, stream>>>(x, xb, 8388608);
    cast_f32_bf16<<<12288, 256, 0, stream>>>(Wqkv_w, wqkvb, 12582912);
    cast_f32_bf16<<<4096, 256, 0, stream>>>(out_w, woutb, 4194304);
    gemm3_qkv<<<768, 512, 0, stream>>>(xb, wqkvb, Wqkv_b, Qb, Kb, Vtb);
    attn_kernel10<<<1024, 256, 0, stream>>>(Qb, Kb, Vtb, attn_bias, Ob);
    gemm3_out<<<256, 512, 0, stream>>>(Ob, woutb, out_b, out);
}

// Round 13
// 345.256 us; speedup vs baseline: 1.0272x; 1.0272x over previous
//
#include <hip/hip_runtime.h>
#include <hip/hip_bf16.h>
#include <stdint.h>

#define H_  16
#define S_  2048
#define D_  2048
#define HD_ 128

typedef __bf16 bf16x8 __attribute__((ext_vector_type(8)));
typedef short  s16x8  __attribute__((ext_vector_type(8)));
typedef float  f32x4  __attribute__((ext_vector_type(4)));
typedef unsigned short u16x4 __attribute__((ext_vector_type(4)));

__device__ __forceinline__ unsigned short f2bf(float f) {
    unsigned u = __builtin_bit_cast(unsigned, f);
    u += 0x7fffu + ((u >> 16) & 1u);
    return (unsigned short)(u >> 16);
}

__device__ __forceinline__ bf16x8 ld_bf8(const unsigned short* p) {
    s16x8 r = *reinterpret_cast<const s16x8*>(p);
    return __builtin_bit_cast(bf16x8, r);
}

#define GLOAD_LDS16(gp, lp)                                                     \
    __builtin_amdgcn_global_load_lds(                                            \
        (const __attribute__((address_space(1))) void*)(gp),                     \
        (__attribute__((address_space(3))) void*)(lp), 16, 0, 0)

// ---------------- cast fp32 -> bf16 ----------------
__global__ __launch_bounds__(256) void cast_f32_bf16(const float* __restrict__ in,
                                                     unsigned short* __restrict__ out,
                                                     int n) {
    int i = (blockIdx.x * 256 + threadIdx.x) * 4;
    if (i >= n) return;
    float4 v = *reinterpret_cast<const float4*>(in + i);
    u16x4 o;
    o[0] = f2bf(v.x); o[1] = f2bf(v.y); o[2] = f2bf(v.z); o[3] = f2bf(v.w);
    *reinterpret_cast<u16x4*>(out + i) = o;
}

// ---------------- QKV GEMM: qkv = x @ W^T + b, scatter Q/K [B,H,S,hd], V as [B,H,hd,S] ----
// 128x128 tile, 16 KB LDS, 84 VGPR -> ~6 blocks/CU co-resident (TLP covers barrier drain).
__global__ __launch_bounds__(256) void gemm_bt_qkv(const unsigned short* __restrict__ A,
                                                   const unsigned short* __restrict__ W,
                                                   const float* __restrict__ bias,
                                                   unsigned short* __restrict__ Qo,
                                                   unsigned short* __restrict__ Ko,
                                                   unsigned short* __restrict__ Vo) {
    __shared__ alignas(16) unsigned short As[128 * 32];
    __shared__ alignas(16) unsigned short Bs[128 * 32];
    const int t  = threadIdx.x;
    const int l  = t & 63, w = t >> 6;
    const int wr = w >> 1, wc = w & 1;
    const int lr = l & 15, g = l >> 4;

    // bijective XCD-chunked swizzle (nwg = 48*32 = 1536, divisible by 8)
    const int GX = 48, NWG = 1536, CPX = NWG / 8;
    const int raw = blockIdx.y * GX + blockIdx.x;
    const int swz = (raw & 7) * CPX + (raw >> 3);
    const int m0 = (swz / GX) * 128, n0 = (swz % GX) * 128;
    const int Kd = D_;

    f32x4 zero = {0.f, 0.f, 0.f, 0.f};
    f32x4 acc[4][4];
    for (int i = 0; i < 4; ++i)
        for (int j = 0; j < 4; ++j) acc[i][j] = zero;

    const int ea = t * 8;
    const int rowA = ea >> 5, colA = ea & 31;

    for (int kt = 0; kt < Kd; kt += 32) {
        GLOAD_LDS16(A + (size_t)(m0 + rowA) * Kd + kt + colA, &As[ea]);
        GLOAD_LDS16(A + (size_t)(m0 + 64 + rowA) * Kd + kt + colA, &As[2048 + ea]);
        GLOAD_LDS16(W + (size_t)(n0 + rowA) * Kd + kt + colA, &Bs[ea]);
        GLOAD_LDS16(W + (size_t)(n0 + 64 + rowA) * Kd + kt + colA, &Bs[2048 + ea]);
        __syncthreads();
        bf16x8 af[4], bfr[4];
        for (int mi = 0; mi < 4; ++mi) af[mi]  = ld_bf8(&As[(wr * 64 + mi * 16 + lr) * 32 + g * 8]);
        for (int ni = 0; ni < 4; ++ni) bfr[ni] = ld_bf8(&Bs[(wc * 64 + ni * 16 + lr) * 32 + g * 8]);
        for (int mi = 0; mi < 4; ++mi)
            for (int ni = 0; ni < 4; ++ni)
                acc[mi][ni] = __builtin_amdgcn_mfma_f32_16x16x32_bf16(af[mi], bfr[ni], acc[mi][ni], 0, 0, 0);
        __syncthreads();
    }

    for (int mi = 0; mi < 4; ++mi) {
        for (int ni = 0; ni < 4; ++ni) {
            for (int i = 0; i < 4; ++i) {
                int m = m0 + wr * 64 + mi * 16 + g * 4 + i;
                int n = n0 + wc * 64 + ni * 16 + lr;
                float v = acc[mi][ni][i] + bias[n];
                int which = n >> 11;
                int n2 = n & 2047;
                int h = n2 >> 7, d = n2 & 127;
                int b = m >> 11, s = m & 2047;
                unsigned short bv = f2bf(v);
                if (which == 0)
                    Qo[(((size_t)(b * H_ + h)) * S_ + s) * HD_ + d] = bv;
                else if (which == 1)
                    Ko[(((size_t)(b * H_ + h)) * S_ + s) * HD_ + d] = bv;
                else  // V transposed in-epilogue: [B,H,hd,S]
                    Vo[(((size_t)(b * H_ + h)) * HD_ + d) * S_ + s] = bv;
            }
        }
    }
}

// ---------------- fused attention v10 + T5 setprio: 32-key chunks, 36 KB LDS ----------
__global__ __launch_bounds__(256) void attn_kernel10(const unsigned short* __restrict__ Q,
                                                     const unsigned short* __restrict__ K,
                                                     const unsigned short* __restrict__ Vt,
                                                     const float* __restrict__ biasPtr,
                                                     unsigned short* __restrict__ O) {
    __shared__ alignas(16) unsigned short Klds[2][4096];      // [32][128] bf16 x2 = 16 KB
    __shared__ alignas(16) unsigned short Vlds[2][4096];      // [128][32] bf16 x2 = 16 KB
    __shared__ alignas(16) unsigned short Pbuf[4][16 * 32];   // 4 KB, per-wave

    const int t  = threadIdx.x;
    const int l  = t & 63, w = t >> 6;
    const int lr = l & 15, g = l >> 4;

    const int raw   = blockIdx.x;          // 0..1023
    const int xcd   = raw & 7;
    const int local = raw >> 3;            // 0..127
    const int cu    = local & 31;
    const int slot  = local >> 5;          // 0..3
    const int qt    = (slot & 1) ? cu : (31 - cu);
    const int bh    = xcd + 8 * slot;      // 0..31
    const int b     = bh >> 4, head = bh & 15;

    const unsigned short* Qb = Q + (size_t)bh * S_ * HD_;
    const unsigned short* Kb = K + (size_t)bh * S_ * HD_;
    const unsigned short* Vb = Vt + (size_t)bh * HD_ * S_;
    const float* Bh32 = biasPtr + (size_t)head * S_ * S_;
    const float scale = 0.08838834764831845f;  // 1/sqrt(128)

    const int q0 = qt * 64 + w * 16;

    bf16x8 qf[4];
#pragma unroll
    for (int dc = 0; dc < 4; ++dc)
        qf[dc] = ld_bf8(Qb + (size_t)(q0 + lr) * HD_ + dc * 32 + g * 8);

    f32x4 zero = {0.f, 0.f, 0.f, 0.f};
    f32x4 o[8];
#pragma unroll
    for (int nc = 0; nc < 8; ++nc) o[nc] = zero;
    float lp[4] = {0.f, 0.f, 0.f, 0.f};

    unsigned short* Pw = Pbuf[w];

    auto STAGE = [&](int buf, int k0) {
#pragma unroll
        for (int p = 0; p < 2; ++p) {
            int lin = p * 4096 + t * 16;           // byte offset in K tile
            int row = lin >> 8;                    // 0..31
            int colb = lin & 255;
            int scolb = colb ^ ((row & 7) << 4);
            GLOAD_LDS16(Kb + (size_t)(k0 + row) * HD_ + (scolb >> 1), &Klds[buf][lin >> 1]);
        }
#pragma unroll
        for (int p = 0; p < 2; ++p) {
            int lin = p * 4096 + t * 16;           // byte offset in Vt tile
            int row = lin >> 6;                    // 0..127 (head dim)
            int colb = lin & 63;
            int scolb = colb ^ ((row & 3) << 4);
            GLOAD_LDS16(Vb + (size_t)row * S_ + k0 + (scolb >> 1), &Vlds[buf][lin >> 1]);
        }
    };

    STAGE(0, 0);
    __syncthreads();

    const int nch = 2 * qt + 2;            // 32-key chunks
    int cur = 0;
    for (int c = 0; c < nch; ++c) {
        const int k0 = c * 32;

        if (c + 1 < nch) STAGE(cur ^ 1, k0 + 32);

        // ---- bias -> registers (fp32 direct; independent loads overlap compute)
        float bias_r[4][2];
#pragma unroll
        for (int i = 0; i < 4; ++i) {
            const int boff = (q0 + g * 4 + i) * S_ + k0 + lr;
#pragma unroll
            for (int kc = 0; kc < 2; ++kc)
                bias_r[i][kc] = Bh32[boff + kc * 16];
        }

        // ---- QK^T from swizzled K LDS (16 q-rows x 32 keys)
        f32x4 s[2];
        s[0] = zero; s[1] = zero;
#pragma unroll
        for (int kc = 0; kc < 2; ++kc) {
            bf16x8 kf[4];
#pragma unroll
            for (int dc = 0; dc < 4; ++dc)
                kf[dc] = ld_bf8(&Klds[cur][(kc * 16 + lr) * 128 + ((dc * 32 + g * 8) ^ ((lr & 7) << 3))]);
            __builtin_amdgcn_s_setprio(1);     // T5: favor MFMA wave vs co-resident loaders
#pragma unroll
            for (int dc = 0; dc < 4; ++dc)
                s[kc] = __builtin_amdgcn_mfma_f32_16x16x32_bf16(qf[dc], kf[dc], s[kc], 0, 0, 0);
            __builtin_amdgcn_s_setprio(0);
        }

        // ---- softmax (fixed shift), P -> per-wave LDS [16][32]
        const bool maskzone = (c >= nch - 2);
#pragma unroll
        for (int i = 0; i < 4; ++i) {
            const int rowabs = q0 + g * 4 + i;
            const int prow   = g * 4 + i;
            float e[2];
#pragma unroll
            for (int kc = 0; kc < 2; ++kc) {
                float v = s[kc][i] * scale + bias_r[i][kc];
                if (maskzone && (k0 + kc * 16 + lr > rowabs)) v = -1.0e30f;
                e[kc] = __expf(v - 16.0f);
            }
            lp[i] += e[0] + e[1];
            const int sw = (prow & 3) << 3;
            Pw[(prow * 32 + 0  + lr) ^ sw] = f2bf(e[0]);
            Pw[(prow * 32 + 16 + lr) ^ sw] = f2bf(e[1]);
        }

        // ---- PV from swizzled V LDS (K=32: single A-fragment per output tile)
        {
            bf16x8 pa = ld_bf8(&Pw[lr * 32 + ((g * 8) ^ ((lr & 3) << 3))]);
            __builtin_amdgcn_s_setprio(1);
#pragma unroll
            for (int nc = 0; nc < 8; ++nc) {
                bf16x8 vf = ld_bf8(&Vlds[cur][(nc * 16 + lr) * 32 + ((g * 8) ^ ((lr & 3) << 3))]);
                o[nc] = __builtin_amdgcn_mfma_f32_16x16x32_bf16(pa, vf, o[nc], 0, 0, 0);
            }
            __builtin_amdgcn_s_setprio(0);
        }

        __syncthreads();   // drains vmcnt: next-chunk staging complete
        cur ^= 1;
    }

    // one-time cross-lane reduction of row sums (over the 16 lr lanes)
#pragma unroll
    for (int i = 0; i < 4; ++i) {
        lp[i] += __shfl_xor(lp[i], 1);
        lp[i] += __shfl_xor(lp[i], 2);
        lp[i] += __shfl_xor(lp[i], 4);
        lp[i] += __shfl_xor(lp[i], 8);
    }

#pragma unroll
    for (int i = 0; i < 4; ++i) {
        float inv = 1.0f / lp[i];
        int row = q0 + g * 4 + i;
#pragma unroll
        for (int nc = 0; nc < 8; ++nc) {
            O[((size_t)(b * S_ + row)) * D_ + head * HD_ + nc * 16 + lr] = f2bf(o[nc][i] * inv);
        }
    }
}

// ---------------- output GEMM: out = O @ Wout^T + b (fp32 out) ----------------
__global__ __launch_bounds__(256) void gemm_bt_out(const unsigned short* __restrict__ A,
                                                   const unsigned short* __restrict__ W,
                                                   const float* __restrict__ bias,
                                                   float* __restrict__ out) {
    __shared__ alignas(16) unsigned short As[128 * 32];
    __shared__ alignas(16) unsigned short Bs[128 * 32];
    const int t  = threadIdx.x;
    const int l  = t & 63, w = t >> 6;
    const int wr = w >> 1, wc = w & 1;
    const int lr = l & 15, g = l >> 4;

    // bijective XCD-chunked swizzle (nwg = 16*32 = 512, divisible by 8)
    const int GX = 16, NWG = 512, CPX = NWG / 8;
    const int raw = blockIdx.y * GX + blockIdx.x;
    const int swz = (raw & 7) * CPX + (raw >> 3);
    const int m0 = (swz / GX) * 128, n0 = (swz % GX) * 128;
    const int Kd = D_;

    f32x4 zero = {0.f, 0.f, 0.f, 0.f};
    f32x4 acc[4][4];
    for (int i = 0; i < 4; ++i)
        for (int j = 0; j < 4; ++j) acc[i][j] = zero;

    const int ea = t * 8;
    const int rowA = ea >> 5, colA = ea & 31;

    for (int kt = 0; kt < Kd; kt += 32) {
        GLOAD_LDS16(A + (size_t)(m0 + rowA) * Kd + kt + colA, &As[ea]);
        GLOAD_LDS16(A + (size_t)(m0 + 64 + rowA) * Kd + kt + colA, &As[2048 + ea]);
        GLOAD_LDS16(W + (size_t)(n0 + rowA) * Kd + kt + colA, &Bs[ea]);
        GLOAD_LDS16(W + (size_t)(n0 + 64 + rowA) * Kd + kt + colA, &Bs[2048 + ea]);
        __syncthreads();
        bf16x8 af[4], bfr[4];
        for (int mi = 0; mi < 4; ++mi) af[mi]  = ld_bf8(&As[(wr * 64 + mi * 16 + lr) * 32 + g * 8]);
        for (int ni = 0; ni < 4; ++ni) bfr[ni] = ld_bf8(&Bs[(wc * 64 + ni * 16 + lr) * 32 + g * 8]);
        for (int mi = 0; mi < 4; ++mi)
            for (int ni = 0; ni < 4; ++ni)
                acc[mi][ni] = __builtin_amdgcn_mfma_f32_16x16x32_bf16(af[mi], bfr[ni], acc[mi][ni], 0, 0, 0);
        __syncthreads();
    }

    for (int mi = 0; mi < 4; ++mi) {
        for (int ni = 0; ni < 4; ++ni) {
            for (int i = 0; i < 4; ++i) {
                int m = m0 + wr * 64 + mi * 16 + g * 4 + i;
                int n = n0 + wc * 64 + ni * 16 + lr;
                out[(size_t)m * D_ + n] = acc[mi][ni][i] + bias[n];
            }
        }
    }
}

extern "C" void kernel_launch(void* const* d_in, const int* in_sizes, int n_in,
                              void* d_out, int out_size, void* d_ws, size_t ws_size,
                              hipStream_t stream) {
    (void)in_sizes; (void)n_in; (void)out_size; (void)ws_size;
    const float* x         = (const float*)d_in[0];
    const float* attn_bias = (const float*)d_in[1];
    const float* Wqkv_w    = (const float*)d_in[2];
    const float* Wqkv_b    = (const float*)d_in[3];
    const float* out_w     = (const float*)d_in[4];
    const float* out_b     = (const float*)d_in[5];
    float* out = (float*)d_out;

    char* ws = (char*)d_ws;
    unsigned short* xb    = (unsigned short*)(ws);                 // 16 MB [B*S, D] bf16
    unsigned short* wqkvb = (unsigned short*)(ws + 16777216);      // 24 MB [3D, D] bf16
    unsigned short* woutb = (unsigned short*)(ws + 41943040);      // 8 MB  [D, D] bf16
    unsigned short* Qb    = (unsigned short*)(ws + 50331648);      // 16 MB [B,H,S,hd]
    unsigned short* Kb    = (unsigned short*)(ws + 67108864);      // 16 MB [B,H,S,hd]
    unsigned short* Vtb   = (unsigned short*)(ws + 83886080);      // 16 MB [B,H,hd,S] (direct)
    unsigned short* Ob    = xb;      // reuse (x consumed by QKV GEMM)

    cast_f32_bf16<<<8192, 256, 0, stream>>>(x, xb, 8388608);
    cast_f32_bf16<<<12288, 256, 0, stream>>>(Wqkv_w, wqkvb, 12582912);
    cast_f32_bf16<<<4096, 256, 0, stream>>>(out_w, woutb, 4194304);
    gemm_bt_qkv<<<dim3(48, 32), 256, 0, stream>>>(xb, wqkvb, Wqkv_b, Qb, Kb, Vtb);
    attn_kernel10<<<1024, 256, 0, stream>>>(Qb, Kb, Vtb, attn_bias, Ob);
    gemm_bt_out<<<dim3(16, 32), 256, 0, stream>>>(Ob, woutb, out_b, out);
}

// Round 14
// 310.971 us; speedup vs baseline: 1.1404x; 1.1103x over previous
//
#include <hip/hip_runtime.h>
#include <hip/hip_bf16.h>
#include <stdint.h>

#define H_  16
#define S_  2048
#define D_  2048
#define HD_ 128

typedef __bf16 bf16x8 __attribute__((ext_vector_type(8)));
typedef short  s16x8  __attribute__((ext_vector_type(8)));
typedef float  f32x4  __attribute__((ext_vector_type(4)));
typedef unsigned short u16x4 __attribute__((ext_vector_type(4)));

__device__ __forceinline__ unsigned short f2bf(float f) {
    unsigned u = __builtin_bit_cast(unsigned, f);
    u += 0x7fffu + ((u >> 16) & 1u);
    return (unsigned short)(u >> 16);
}

__device__ __forceinline__ bf16x8 ld_bf8(const unsigned short* p) {
    s16x8 r = *reinterpret_cast<const s16x8*>(p);
    return __builtin_bit_cast(bf16x8, r);
}

#define GLOAD_LDS16(gp, lp)                                                     \
    __builtin_amdgcn_global_load_lds(                                            \
        (const __attribute__((address_space(1))) void*)(gp),                     \
        (__attribute__((address_space(3))) void*)(lp), 16, 0, 0)

// ---------------- cast fp32 -> bf16 ----------------
__global__ __launch_bounds__(256) void cast_f32_bf16(const float* __restrict__ in,
                                                     unsigned short* __restrict__ out,
                                                     int n) {
    int i = (blockIdx.x * 256 + threadIdx.x) * 4;
    if (i >= n) return;
    float4 v = *reinterpret_cast<const float4*>(in + i);
    u16x4 o;
    o[0] = f2bf(v.x); o[1] = f2bf(v.y); o[2] = f2bf(v.z); o[3] = f2bf(v.w);
    *reinterpret_cast<u16x4*>(out + i) = o;
}

// ======= 128x128 GEMM core, BK=64, both-sides XOR swizzle (conflict-free ds_read) =======
// 32 KB LDS, ~5 blocks/CU. Per K-iter: 8 gload_lds (pre-swizzled source), 1 barrier pair,
// 16 ds_read_b128 (swizzled, 2-way max), 32 MFMA. Half the barriers of BK=32.
__device__ __forceinline__ void gemm128_core(const unsigned short* __restrict__ Aptr,
                                             const unsigned short* __restrict__ Bptr,
                                             int m0, int n0,
                                             unsigned short* As, unsigned short* Bs,
                                             f32x4 acc[4][4]) {
    const int t  = threadIdx.x;
    const int l  = t & 63, w = t >> 6;
    const int wr = w >> 1, wc = w & 1;
    const int lr = l & 15, g = l >> 4;

    f32x4 zero = {0.f, 0.f, 0.f, 0.f};
#pragma unroll
    for (int i = 0; i < 4; ++i)
#pragma unroll
        for (int j = 0; j < 4; ++j) acc[i][j] = zero;

    for (int kt = 0; kt < D_; kt += 64) {
#pragma unroll
        for (int p = 0; p < 4; ++p) {
            int lin = (p * 256 + t) * 16;          // byte offset in [128][128B] tile
            int row = lin >> 7, colb = lin & 127;
            int scol = (colb ^ ((row & 7) << 4)) >> 1;
            GLOAD_LDS16(Aptr + (size_t)(m0 + row) * D_ + kt + scol, &As[lin >> 1]);
        }
#pragma unroll
        for (int p = 0; p < 4; ++p) {
            int lin = (p * 256 + t) * 16;
            int row = lin >> 7, colb = lin & 127;
            int scol = (colb ^ ((row & 7) << 4)) >> 1;
            GLOAD_LDS16(Bptr + (size_t)(n0 + row) * D_ + kt + scol, &Bs[lin >> 1]);
        }
        __syncthreads();
#pragma unroll
        for (int ks = 0; ks < 2; ++ks) {
            bf16x8 af[4], bfr[4];
#pragma unroll
            for (int mi = 0; mi < 4; ++mi)
                af[mi] = ld_bf8(&As[(wr * 64 + mi * 16 + lr) * 64 +
                                    ((ks * 32 + g * 8) ^ ((lr & 7) << 3))]);
#pragma unroll
            for (int ni = 0; ni < 4; ++ni)
                bfr[ni] = ld_bf8(&Bs[(wc * 64 + ni * 16 + lr) * 64 +
                                     ((ks * 32 + g * 8) ^ ((lr & 7) << 3))]);
#pragma unroll
            for (int mi = 0; mi < 4; ++mi)
#pragma unroll
                for (int ni = 0; ni < 4; ++ni)
                    acc[mi][ni] = __builtin_amdgcn_mfma_f32_16x16x32_bf16(
                        af[mi], bfr[ni], acc[mi][ni], 0, 0, 0);
        }
        __syncthreads();
    }
}

// ---------------- QKV GEMM: scatter Q/K [B,H,S,hd], V as [B,H,hd,S] (vectorized) ----------
__global__ __launch_bounds__(256) void gemm_bt_qkv(const unsigned short* __restrict__ A,
                                                   const unsigned short* __restrict__ W,
                                                   const float* __restrict__ bias,
                                                   unsigned short* __restrict__ Qo,
                                                   unsigned short* __restrict__ Ko,
                                                   unsigned short* __restrict__ Vo) {
    __shared__ alignas(16) unsigned short As[128 * 64];
    __shared__ alignas(16) unsigned short Bs[128 * 64];

    // bijective XCD-chunked swizzle (nwg = 48*32 = 1536, divisible by 8)
    const int GX = 48, NWG = 1536, CPX = NWG / 8;
    const int raw = blockIdx.y * GX + blockIdx.x;
    const int swz = (raw & 7) * CPX + (raw >> 3);
    const int m0 = (swz / GX) * 128, n0 = (swz % GX) * 128;

    f32x4 acc[4][4];
    gemm128_core(A, W, m0, n0, As, Bs, acc);

    const int l  = threadIdx.x & 63, w = threadIdx.x >> 6;
    const int wr = w >> 1, wc = w & 1;
    const int lr = l & 15, g = l >> 4;

    // block-constant output routing (128-wide n-tile spans exactly one which/head;
    // 128-high m-tile spans one batch)
    const int which = n0 >> 11;
    const int h     = (n0 & 2047) >> 7;
    const int b     = m0 >> 11;
    const int sb    = m0 & 2047;

    float bias_v[4];
#pragma unroll
    for (int ni = 0; ni < 4; ++ni)
        bias_v[ni] = bias[n0 + wc * 64 + ni * 16 + lr];

    if (which == 2) {
        // V transposed in-epilogue: [B,H,hd,S]; 4 consecutive s per lane -> u16x4 store
        unsigned short* Vb = Vo + ((size_t)(b * H_ + h)) * HD_ * S_;
#pragma unroll
        for (int mi = 0; mi < 4; ++mi) {
#pragma unroll
            for (int ni = 0; ni < 4; ++ni) {
                int d = wc * 64 + ni * 16 + lr;
                int s = sb + wr * 64 + mi * 16 + g * 4;
                u16x4 pv;
#pragma unroll
                for (int i = 0; i < 4; ++i) pv[i] = f2bf(acc[mi][ni][i] + bias_v[ni]);
                *reinterpret_cast<u16x4*>(&Vb[(size_t)d * S_ + s]) = pv;
            }
        }
    } else {
        unsigned short* Pb = ((which == 0) ? Qo : Ko) + ((size_t)(b * H_ + h)) * S_ * HD_;
#pragma unroll
        for (int mi = 0; mi < 4; ++mi) {
#pragma unroll
            for (int ni = 0; ni < 4; ++ni) {
                int d = wc * 64 + ni * 16 + lr;
#pragma unroll
                for (int i = 0; i < 4; ++i) {
                    int s = sb + wr * 64 + mi * 16 + g * 4 + i;
                    Pb[(size_t)s * HD_ + d] = f2bf(acc[mi][ni][i] + bias_v[ni]);
                }
            }
        }
    }
}

// ---------------- output GEMM: out = O @ Wout^T + b (fp32 out) ----------------
__global__ __launch_bounds__(256) void gemm_bt_out(const unsigned short* __restrict__ A,
                                                   const unsigned short* __restrict__ W,
                                                   const float* __restrict__ bias,
                                                   float* __restrict__ out) {
    __shared__ alignas(16) unsigned short As[128 * 64];
    __shared__ alignas(16) unsigned short Bs[128 * 64];

    // bijective XCD-chunked swizzle (nwg = 16*32 = 512, divisible by 8)
    const int GX = 16, NWG = 512, CPX = NWG / 8;
    const int raw = blockIdx.y * GX + blockIdx.x;
    const int swz = (raw & 7) * CPX + (raw >> 3);
    const int m0 = (swz / GX) * 128, n0 = (swz % GX) * 128;

    f32x4 acc[4][4];
    gemm128_core(A, W, m0, n0, As, Bs, acc);

    const int l  = threadIdx.x & 63, w = threadIdx.x >> 6;
    const int wr = w >> 1, wc = w & 1;
    const int lr = l & 15, g = l >> 4;

    for (int mi = 0; mi < 4; ++mi) {
        for (int ni = 0; ni < 4; ++ni) {
            for (int i = 0; i < 4; ++i) {
                int m = m0 + wr * 64 + mi * 16 + g * 4 + i;
                int n = n0 + wc * 64 + ni * 16 + lr;
                out[(size_t)m * D_ + n] = acc[mi][ni][i] + bias[n];
            }
        }
    }
}

// ---------------- fused attention v10 (round-10 verified; NO setprio) ----------
__global__ __launch_bounds__(256) void attn_kernel10(const unsigned short* __restrict__ Q,
                                                     const unsigned short* __restrict__ K,
                                                     const unsigned short* __restrict__ Vt,
                                                     const float* __restrict__ biasPtr,
                                                     unsigned short* __restrict__ O) {
    __shared__ alignas(16) unsigned short Klds[2][4096];      // [32][128] bf16 x2 = 16 KB
    __shared__ alignas(16) unsigned short Vlds[2][4096];      // [128][32] bf16 x2 = 16 KB
    __shared__ alignas(16) unsigned short Pbuf[4][16 * 32];   // 4 KB, per-wave

    const int t  = threadIdx.x;
    const int l  = t & 63, w = t >> 6;
    const int lr = l & 15, g = l >> 4;

    const int raw   = blockIdx.x;          // 0..1023
    const int xcd   = raw & 7;
    const int local = raw >> 3;            // 0..127
    const int cu    = local & 31;
    const int slot  = local >> 5;          // 0..3
    const int qt    = (slot & 1) ? cu : (31 - cu);
    const int bh    = xcd + 8 * slot;      // 0..31
    const int b     = bh >> 4, head = bh & 15;

    const unsigned short* Qb = Q + (size_t)bh * S_ * HD_;
    const unsigned short* Kb = K + (size_t)bh * S_ * HD_;
    const unsigned short* Vb = Vt + (size_t)bh * HD_ * S_;
    const float* Bh32 = biasPtr + (size_t)head * S_ * S_;
    const float scale = 0.08838834764831845f;  // 1/sqrt(128)

    const int q0 = qt * 64 + w * 16;

    bf16x8 qf[4];
#pragma unroll
    for (int dc = 0; dc < 4; ++dc)
        qf[dc] = ld_bf8(Qb + (size_t)(q0 + lr) * HD_ + dc * 32 + g * 8);

    f32x4 zero = {0.f, 0.f, 0.f, 0.f};
    f32x4 o[8];
#pragma unroll
    for (int nc = 0; nc < 8; ++nc) o[nc] = zero;
    float lp[4] = {0.f, 0.f, 0.f, 0.f};

    unsigned short* Pw = Pbuf[w];

    auto STAGE = [&](int buf, int k0) {
#pragma unroll
        for (int p = 0; p < 2; ++p) {
            int lin = p * 4096 + t * 16;           // byte offset in K tile
            int row = lin >> 8;                    // 0..31
            int colb = lin & 255;
            int scolb = colb ^ ((row & 7) << 4);
            GLOAD_LDS16(Kb + (size_t)(k0 + row) * HD_ + (scolb >> 1), &Klds[buf][lin >> 1]);
        }
#pragma unroll
        for (int p = 0; p < 2; ++p) {
            int lin = p * 4096 + t * 16;           // byte offset in Vt tile
            int row = lin >> 6;                    // 0..127 (head dim)
            int colb = lin & 63;
            int scolb = colb ^ ((row & 3) << 4);
            GLOAD_LDS16(Vb + (size_t)row * S_ + k0 + (scolb >> 1), &Vlds[buf][lin >> 1]);
        }
    };

    STAGE(0, 0);
    __syncthreads();

    const int nch = 2 * qt + 2;            // 32-key chunks
    int cur = 0;
    for (int c = 0; c < nch; ++c) {
        const int k0 = c * 32;

        if (c + 1 < nch) STAGE(cur ^ 1, k0 + 32);

        // ---- bias -> registers (fp32 direct; independent loads overlap compute)
        float bias_r[4][2];
#pragma unroll
        for (int i = 0; i < 4; ++i) {
            const int boff = (q0 + g * 4 + i) * S_ + k0 + lr;
#pragma unroll
            for (int kc = 0; kc < 2; ++kc)
                bias_r[i][kc] = Bh32[boff + kc * 16];
        }

        // ---- QK^T from swizzled K LDS (16 q-rows x 32 keys)
        f32x4 s[2];
        s[0] = zero; s[1] = zero;
#pragma unroll
        for (int kc = 0; kc < 2; ++kc) {
            bf16x8 kf[4];
#pragma unroll
            for (int dc = 0; dc < 4; ++dc)
                kf[dc] = ld_bf8(&Klds[cur][(kc * 16 + lr) * 128 + ((dc * 32 + g * 8) ^ ((lr & 7) << 3))]);
#pragma unroll
            for (int dc = 0; dc < 4; ++dc)
                s[kc] = __builtin_amdgcn_mfma_f32_16x16x32_bf16(qf[dc], kf[dc], s[kc], 0, 0, 0);
        }

        // ---- softmax (fixed shift), P -> per-wave LDS [16][32]
        const bool maskzone = (c >= nch - 2);
#pragma unroll
        for (int i = 0; i < 4; ++i) {
            const int rowabs = q0 + g * 4 + i;
            const int prow   = g * 4 + i;
            float e[2];
#pragma unroll
            for (int kc = 0; kc < 2; ++kc) {
                float v = s[kc][i] * scale + bias_r[i][kc];
                if (maskzone && (k0 + kc * 16 + lr > rowabs)) v = -1.0e30f;
                e[kc] = __expf(v - 16.0f);
            }
            lp[i] += e[0] + e[1];
            const int sw = (prow & 3) << 3;
            Pw[(prow * 32 + 0  + lr) ^ sw] = f2bf(e[0]);
            Pw[(prow * 32 + 16 + lr) ^ sw] = f2bf(e[1]);
        }

        // ---- PV from swizzled V LDS (K=32: single A-fragment per output tile)
        {
            bf16x8 pa = ld_bf8(&Pw[lr * 32 + ((g * 8) ^ ((lr & 3) << 3))]);
#pragma unroll
            for (int nc = 0; nc < 8; ++nc) {
                bf16x8 vf = ld_bf8(&Vlds[cur][(nc * 16 + lr) * 32 + ((g * 8) ^ ((lr & 3) << 3))]);
                o[nc] = __builtin_amdgcn_mfma_f32_16x16x32_bf16(pa, vf, o[nc], 0, 0, 0);
            }
        }

        __syncthreads();   // drains vmcnt: next-chunk staging complete
        cur ^= 1;
    }

    // one-time cross-lane reduction of row sums (over the 16 lr lanes)
#pragma unroll
    for (int i = 0; i < 4; ++i) {
        lp[i] += __shfl_xor(lp[i], 1);
        lp[i] += __shfl_xor(lp[i], 2);
        lp[i] += __shfl_xor(lp[i], 4);
        lp[i] += __shfl_xor(lp[i], 8);
    }

#pragma unroll
    for (int i = 0; i < 4; ++i) {
        float inv = 1.0f / lp[i];
        int row = q0 + g * 4 + i;
#pragma unroll
        for (int nc = 0; nc < 8; ++nc) {
            O[((size_t)(b * S_ + row)) * D_ + head * HD_ + nc * 16 + lr] = f2bf(o[nc][i] * inv);
        }
    }
}

extern "C" void kernel_launch(void* const* d_in, const int* in_sizes, int n_in,
                              void* d_out, int out_size, void* d_ws, size_t ws_size,
                              hipStream_t stream) {
    (void)in_sizes; (void)n_in; (void)out_size; (void)ws_size;
    const float* x         = (const float*)d_in[0];
    const float* attn_bias = (const float*)d_in[1];
    const float* Wqkv_w    = (const float*)d_in[2];
    const float* Wqkv_b    = (const float*)d_in[3];
    const float* out_w     = (const float*)d_in[4];
    const float* out_b     = (const float*)d_in[5];
    float* out = (float*)d_out;

    char* ws = (char*)d_ws;
    unsigned short* xb    = (unsigned short*)(ws);                 // 16 MB [B*S, D] bf16
    unsigned short* wqkvb = (unsigned short*)(ws + 16777216);      // 24 MB [3D, D] bf16
    unsigned short* woutb = (unsigned short*)(ws + 41943040);      // 8 MB  [D, D] bf16
    unsigned short* Qb    = (unsigned short*)(ws + 50331648);      // 16 MB [B,H,S,hd]
    unsigned short* Kb    = (unsigned short*)(ws + 67108864);      // 16 MB [B,H,S,hd]
    unsigned short* Vtb   = (unsigned short*)(ws + 83886080);      // 16 MB [B,H,hd,S] (direct)
    unsigned short* Ob    = xb;      // reuse (x consumed by QKV GEMM)

    cast_f32_bf16<<<8192, 256, 0, stream>>>(x, xb, 8388608);
    cast_f32_bf16<<<12288, 256, 0, stream>>>(Wqkv_w, wqkvb, 12582912);
    cast_f32_bf16<<<4096, 256, 0, stream>>>(out_w, woutb, 4194304);
    gemm_bt_qkv<<<dim3(48, 32), 256, 0, stream>>>(xb, wqkvb, Wqkv_b, Qb, Kb, Vtb);
    attn_kernel10<<<1024, 256, 0, stream>>>(Qb, Kb, Vtb, attn_bias, Ob);
    gemm_bt_out<<<dim3(16, 32), 256, 0, stream>>>(Ob, woutb, out_b, out);
}